// Round 3
// baseline (282.568 us; speedup 1.0000x reference)
//
#include <hip/hip_runtime.h>
#include <hip/hip_bf16.h>

typedef __bf16 bf16;
typedef __attribute__((ext_vector_type(8))) __bf16 bf16x8;
typedef __attribute__((ext_vector_type(4))) float f32x4;

namespace {
constexpr int SEQ  = 2048;
constexpr int TQ   = 64;
constexpr int TS   = 64;
constexpr int ROWB = 144;   // row pitch bytes (8×16B chunks used + 1 pad chunk)
constexpr int SPAD = 72;    // P row pitch (bf16)
constexpr int OPAD = 68;    // epilogue f32 row pitch
// chunk swizzle: both write & read XOR the 16B-chunk index with this
__device__ __forceinline__ int swz_row(int row) {
    return (((row >> 2) & 3) << 1) | ((row >> 4) & 1);
}
}

__global__ __launch_bounds__(256, 5)
void qkv_attn_kernel(const float* __restrict__ qkv, float* __restrict__ out) {
    // XCD-chunked remap: 2048 blocks, 8 XCDs -> each head's 32 blocks on one XCD
    const int bid  = (blockIdx.x & 7) * 256 + (blockIdx.x >> 3);
    const int head = bid >> 5;
    const int t0   = (bid & 31) * TQ;
    const int tid  = threadIdx.x;
    const int lane = tid & 63;
    const int w    = tid >> 6;            // wave 0..3
    const int g    = lane >> 4;           // 0..3
    const int lr   = lane & 15;

    __shared__ __align__(16) char smem[3 * 64 * ROWB];      // 27648 B
    char* Qb = smem;                                         // [64][144] swizzled; becomes Ps
    char* Kb = smem + 64*ROWB;                               // [s][c] swizzled
    char* Vb = smem + 2*64*ROWB;                             // [c][s] swizzled
    bf16 (*Ps)[SPAD] = (bf16(*)[SPAD])(smem);                // [t][s] (overlays Qb)
    float* Os = (float*)(smem + 64*ROWB);                    // epilogue [64][OPAD] = 17408B

    const float* qbase = qkv + (size_t)(head*192 +   0) * SEQ + t0;
    const float* kbase = qkv + (size_t)(head*192 +  64) * SEQ;
    const float* vbase = qkv + (size_t)(head*192 + 128) * SEQ;

    // staging map: c = cl + 16*it (16 c per wave), rows r4..r4+3
    const int cl = tid & 15;
    const int mq = tid >> 4;               // 0..15 (4w..4w+3 within wave)
    const int r4 = mq * 4;
    const int sw = ((mq & 3) << 1) | ((mq >> 2) & 1);   // == swz_row(r4+j)

    // ---- stage Q once; fold scale^2 * log2(e) so softmax uses exp2
    {
        constexpr float QS = 0.125f * 1.4426950408889634f;
        #pragma unroll
        for (int it = 0; it < 4; ++it) {
            const int c = cl + it*16;
            const float4 v = *(const float4*)(qbase + (size_t)c * SEQ + r4);
            const int coff = ((((c >> 3) ^ sw) << 4) | ((c & 7) << 1));
            *(bf16*)(Qb + (r4+0)*ROWB + coff) = (bf16)(v.x * QS);
            *(bf16*)(Qb + (r4+1)*ROWB + coff) = (bf16)(v.y * QS);
            *(bf16*)(Qb + (r4+2)*ROWB + coff) = (bf16)(v.z * QS);
            *(bf16*)(Qb + (r4+3)*ROWB + coff) = (bf16)(v.w * QS);
        }
    }
    __syncthreads();

    // ---- hoist Q fragments; afterwards Qb rows w*16..w*16+15 are wave-private (Ps)
    bf16x8 aq[2];
    {
        const int trow = w*16 + lr;
        const int tsw  = swz_row(trow);
        #pragma unroll
        for (int ks = 0; ks < 2; ++ks)
            aq[ks] = *(const bf16x8*)(Qb + trow*ROWB + ((((ks<<2)|g) ^ tsw) << 4));
    }

    // ---- prefetch tile 0
    float4 kf[4], vf[4];
    #pragma unroll
    for (int it = 0; it < 4; ++it) {
        const int c = cl + it*16;
        kf[it] = *(const float4*)(kbase + (size_t)c * SEQ + r4);
        vf[it] = *(const float4*)(vbase + (size_t)c * SEQ + r4);
    }

    float m_l = -1e30f, l_l = 0.f;
    f32x4 oacc[4];
    #pragma unroll
    for (int f = 0; f < 4; ++f) oacc[f] = f32x4{0.f, 0.f, 0.f, 0.f};

    for (int s0 = 0; s0 < SEQ; s0 += TS) {
        // ---- regs -> LDS: K as [s][c] (scalar, swizzled), V as [c][s] (uint2, swizzled)
        #pragma unroll
        for (int it = 0; it < 4; ++it) {
            const int c = cl + it*16;
            const int coff = ((((c >> 3) ^ sw) << 4) | ((c & 7) << 1));
            *(bf16*)(Kb + (r4+0)*ROWB + coff) = (bf16)kf[it].x;
            *(bf16*)(Kb + (r4+1)*ROWB + coff) = (bf16)kf[it].y;
            *(bf16*)(Kb + (r4+2)*ROWB + coff) = (bf16)kf[it].z;
            *(bf16*)(Kb + (r4+3)*ROWB + coff) = (bf16)kf[it].w;
            union { bf16 h[4]; uint2 u; } pk;
            pk.h[0] = (bf16)vf[it].x; pk.h[1] = (bf16)vf[it].y;
            pk.h[2] = (bf16)vf[it].z; pk.h[3] = (bf16)vf[it].w;
            const int voff = ((((mq >> 1) ^ swz_row(c)) << 4) | ((mq & 1) << 3));
            *(uint2*)(Vb + c*ROWB + voff) = pk.u;
        }
        __syncthreads();

        // ---- issue next tile's global loads (drain at next write phase)
        if (s0 + TS < SEQ) {
            #pragma unroll
            for (int it = 0; it < 4; ++it) {
                const int c = cl + it*16;
                kf[it] = *(const float4*)(kbase + (size_t)c * SEQ + (s0 + TS) + r4);
                vf[it] = *(const float4*)(vbase + (size_t)c * SEQ + (s0 + TS) + r4);
            }
        }

        // ---- S^T = mfma(K, Q): lane (g,lr) holds S[s=16f+4g+r][t=w*16+lr]
        f32x4 sacc[4];
        #pragma unroll
        for (int f = 0; f < 4; ++f) sacc[f] = f32x4{0.f,0.f,0.f,0.f};
        #pragma unroll
        for (int ks = 0; ks < 2; ++ks) {
            #pragma unroll
            for (int f = 0; f < 4; ++f) {
                const int srow = f*16 + lr;
                const bf16x8 bk = *(const bf16x8*)(Kb + srow*ROWB +
                                    ((((ks<<2)|g) ^ swz_row(srow)) << 4));
                sacc[f] = __builtin_amdgcn_mfma_f32_16x16x32_bf16(bk, aq[ks], sacc[f], 0, 0, 0);
            }
        }

        // ---- online softmax, lane-local in t (base-2 domain)
        f32x4 mx01, mx23;
        #pragma unroll
        for (int r = 0; r < 4; ++r) {
            mx01[r] = fmaxf(sacc[0][r], sacc[1][r]);
            mx23[r] = fmaxf(sacc[2][r], sacc[3][r]);
        }
        float tm = fmaxf(fmaxf(fmaxf(mx01[0], mx01[1]), fmaxf(mx01[2], mx01[3])),
                         fmaxf(fmaxf(mx23[0], mx23[1]), fmaxf(mx23[2], mx23[3])));
        tm = fmaxf(tm, __shfl_xor(tm, 16));
        tm = fmaxf(tm, __shfl_xor(tm, 32));
        const float mn    = fmaxf(m_l, tm);
        const float alpha = __builtin_amdgcn_exp2f(m_l - mn);
        m_l = mn;
        float rs = 0.f;
        #pragma unroll
        for (int f = 0; f < 4; ++f) {
            #pragma unroll
            for (int r = 0; r < 4; ++r) {
                const float p = __builtin_amdgcn_exp2f(sacc[f][r] - mn);
                sacc[f][r] = p;
                rs += p;
            }
        }
        rs += __shfl_xor(rs, 16);
        rs += __shfl_xor(rs, 32);
        l_l = l_l * alpha + rs;
        #pragma unroll
        for (int f = 0; f < 4; ++f)
            #pragma unroll
            for (int r = 0; r < 4; ++r)
                oacc[f][r] *= alpha;

        // ---- P^T -> Ps[t][s]: 4 packed uint2 writes (wave-private rows)
        #pragma unroll
        for (int f = 0; f < 4; ++f) {
            union { bf16 h[4]; uint2 u; } pk;
            pk.h[0] = (bf16)sacc[f][0]; pk.h[1] = (bf16)sacc[f][1];
            pk.h[2] = (bf16)sacc[f][2]; pk.h[3] = (bf16)sacc[f][3];
            *(uint2*)&Ps[w*16 + lr][f*16 + g*4] = pk.u;
        }

        // ---- O(c,t) += V(c,s) P(s,t): mfma(V, P); t = w*16+lr stays lane-local
        #pragma unroll
        for (int ks = 0; ks < 2; ++ks) {
            const bf16x8 bp = *(const bf16x8*)&Ps[w*16 + lr][ks*32 + g*8];
            #pragma unroll
            for (int f = 0; f < 4; ++f) {
                const int vrow = f*16 + lr;
                const bf16x8 av = *(const bf16x8*)(Vb + vrow*ROWB +
                                    ((((ks<<2)|g) ^ swz_row(vrow)) << 4));
                oacc[f] = __builtin_amdgcn_mfma_f32_16x16x32_bf16(av, bp, oacc[f], 0, 0, 0);
            }
        }
        __syncthreads();   // all waves done with Kb/Vb before next overwrite
    }

    // ---- epilogue: O(c,t)/l -> Os[c][t] (lane-local inv), then coalesced out
    {
        const float inv = 1.0f / l_l;
        #pragma unroll
        for (int f = 0; f < 4; ++f)
            #pragma unroll
            for (int r = 0; r < 4; ++r)
                Os[(f*16 + g*4 + r) * OPAD + (w*16 + lr)] = oacc[f][r] * inv;
    }
    __syncthreads();
    {
        const int ce = tid >> 4;          // 0..15
        const int te = (tid & 15) * 4;
        #pragma unroll
        for (int it = 0; it < 4; ++it) {
            const int c = ce + it*16;
            *(float4*)(out + (size_t)(head*64 + c) * SEQ + t0 + te) =
                *(const float4*)&Os[c * OPAD + te];
        }
    }
}

extern "C" void kernel_launch(void* const* d_in, const int* in_sizes, int n_in,
                              void* d_out, int out_size, void* d_ws, size_t ws_size,
                              hipStream_t stream) {
    const float* qkv = (const float*)d_in[0];
    float* out = (float*)d_out;
    qkv_attn_kernel<<<dim3(2048), dim3(256), 0, stream>>>(qkv, out);
}

// Round 4
// 134.664 us; speedup vs baseline: 2.0983x; 2.0983x over previous
//
#include <hip/hip_runtime.h>
#include <hip/hip_bf16.h>

typedef __bf16 bf16;
typedef __attribute__((ext_vector_type(8))) __bf16 bf16x8;
typedef __attribute__((ext_vector_type(16))) float f32x16;
typedef __attribute__((ext_vector_type(2))) unsigned uint2v;

namespace {
constexpr int SEQ  = 2048;
constexpr int ROWB = 144;   // row pitch bytes: 8 used 16B chunks + 1 pad chunk
}

__device__ __forceinline__ unsigned cvt_pk_bf16(float lo, float hi) {
    unsigned r;
    asm("v_cvt_pk_bf16_f32 %0, %1, %2" : "=v"(r) : "v"(lo), "v"(hi));
    return r;
}

__global__ __launch_bounds__(256, 3)
void qkv_attn_kernel(const float* __restrict__ qkv, float* __restrict__ out) {
    // 64 heads x 16 t-tiles(128) = 1024 blocks; XCD-chunked remap
    const int orig = blockIdx.x;
    const int bid  = (orig & 7) * 128 + (orig >> 3);
    const int head = bid >> 4;
    const int t0   = (bid & 15) * 128;
    const int tid  = threadIdx.x;
    const int w    = tid >> 6;            // wave 0..3 -> t chunk [32w, 32w+32)
    const int lam  = tid & 31;            // lane&31
    const int h    = (tid >> 5) & 1;      // lane>>5

    __shared__ __align__(16) char smem[128 * ROWB];   // 18432 B
    char* Qb = smem;                                   // [128 t][144] (staging only)
    char* Kb = smem;                                   // [64 s][144]  (after Q hoist)
    char* Vb = smem + 64 * ROWB;                       // [64 c][144]

    const float* qbase = qkv + (size_t)(head*192 +   0) * SEQ + t0;
    const float* kbase = qkv + (size_t)(head*192 +  64) * SEQ;
    const float* vbase = qkv + (size_t)(head*192 + 128) * SEQ;

    // staging map: c = cl + 16*it, rows 4*mq .. 4*mq+3
    const int cl = tid & 15;
    const int mq = tid >> 4;                            // 0..15
    const int sw = ((mq & 3) << 1) | ((mq >> 2) & 1);   // swz of rows 4mq..4mq+3 (+64)

    // ---- stage Q[128][64] once; fold scale^2*log2(e) for exp2-domain softmax
    {
        constexpr float QS = 0.125f * 1.4426950408889634f;
        #pragma unroll
        for (int tau = 0; tau < 2; ++tau) {
            #pragma unroll
            for (int it = 0; it < 4; ++it) {
                const int c = cl + it*16;
                const int trow = tau*64 + mq*4;
                const float4 v = *(const float4*)(qbase + (size_t)c * SEQ + trow);
                const int coff = (((c >> 3) ^ sw) << 4) | ((c & 7) << 1);
                char* b = Qb + trow*ROWB + coff;
                *(bf16*)(b + 0*ROWB) = (bf16)(v.x * QS);
                *(bf16*)(b + 1*ROWB) = (bf16)(v.y * QS);
                *(bf16*)(b + 2*ROWB) = (bf16)(v.z * QS);
                *(bf16*)(b + 3*ROWB) = (bf16)(v.w * QS);
            }
        }
    }
    __syncthreads();

    // ---- hoist Q fragments: B-operand, col t = 32w+lam, k = c = 16ks+8h+j
    bf16x8 aq[4];
    {
        const int trow = 32*w + lam;
        const int swq  = (((lam >> 2) & 3) << 1) | ((lam >> 4) & 1);
        #pragma unroll
        for (int ks = 0; ks < 4; ++ks)
            aq[ks] = *(const bf16x8*)(Qb + trow*ROWB + (((2*ks + h) ^ swq) << 4));
    }
    __syncthreads();   // Q reads done before K/V staging overwrites

    // ---- prefetch tile 0
    float4 kf[4], vf[4];
    #pragma unroll
    for (int it = 0; it < 4; ++it) {
        const int c = cl + it*16;
        kf[it] = *(const float4*)(kbase + (size_t)c * SEQ + mq*4);
        vf[it] = *(const float4*)(vbase + (size_t)c * SEQ + mq*4);
    }

    float m_l = -1e30f, l_l = 0.f;
    f32x16 oacc[2];
    #pragma unroll
    for (int p = 0; p < 2; ++p)
        #pragma unroll
        for (int r = 0; r < 16; ++r) oacc[p][r] = 0.f;

    const int swk = (((lam >> 2) & 3) << 1) | ((lam >> 4) & 1);  // K-row swizzle (rows ≡ lam mod 32)
    const int swv = (lam >> 1) & 7;                              // V-row swizzle

    for (int s0 = 0; s0 < SEQ; s0 += 64) {
        // ---- regs -> LDS: K[s][c] scalar transpose; V[c][s] packed uint2
        #pragma unroll
        for (int it = 0; it < 4; ++it) {
            const int c = cl + it*16;
            const int coff = (((c >> 3) ^ sw) << 4) | ((c & 7) << 1);
            char* b = Kb + (mq*4)*ROWB + coff;
            *(bf16*)(b + 0*ROWB) = (bf16)kf[it].x;
            *(bf16*)(b + 1*ROWB) = (bf16)kf[it].y;
            *(bf16*)(b + 2*ROWB) = (bf16)kf[it].z;
            *(bf16*)(b + 3*ROWB) = (bf16)kf[it].w;
            union { bf16 hh[4]; uint2 u; } pk;
            pk.hh[0] = (bf16)vf[it].x; pk.hh[1] = (bf16)vf[it].y;
            pk.hh[2] = (bf16)vf[it].z; pk.hh[3] = (bf16)vf[it].w;
            const int voff = (((mq >> 1) ^ ((c >> 1) & 7)) << 4) | ((mq & 1) << 3);
            *(uint2*)(Vb + c*ROWB + voff) = pk.u;
        }
        __syncthreads();

        // ---- issue next tile's global loads (stay in regs through compute)
        if (s0 + 64 < SEQ) {
            #pragma unroll
            for (int it = 0; it < 4; ++it) {
                const int c = cl + it*16;
                kf[it] = *(const float4*)(kbase + (size_t)c * SEQ + (s0 + 64) + mq*4);
                vf[it] = *(const float4*)(vbase + (size_t)c * SEQ + (s0 + 64) + mq*4);
            }
        }

        // ---- S^T = mfma32(K, Q): D[s][t]; s = 32*spos + (r&3)+8*(r>>2)+4h, t = 32w+lam
        f32x16 sacc[2];
        #pragma unroll
        for (int p = 0; p < 2; ++p)
            #pragma unroll
            for (int r = 0; r < 16; ++r) sacc[p][r] = 0.f;
        #pragma unroll
        for (int ks = 0; ks < 4; ++ks) {
            #pragma unroll
            for (int spos = 0; spos < 2; ++spos) {
                const bf16x8 ak = *(const bf16x8*)(Kb + (32*spos + lam)*ROWB +
                                                   (((2*ks + h) ^ swk) << 4));
                sacc[spos] = __builtin_amdgcn_mfma_f32_32x32x16_bf16(ak, aq[ks], sacc[spos], 0, 0, 0);
            }
        }

        // ---- online softmax (lane-local t; partner lane^32 holds the other 32 s)
        float tm;
        {
            f32x16 mx;
            #pragma unroll
            for (int r = 0; r < 16; ++r) mx[r] = fmaxf(sacc[0][r], sacc[1][r]);
            #pragma unroll
            for (int d = 8; d >= 1; d >>= 1)
                #pragma unroll
                for (int r = 0; r < d; ++r) mx[r] = fmaxf(mx[r], mx[r + d]);
            tm = mx[0];
        }
        tm = fmaxf(tm, __shfl_xor(tm, 32));
        if (!__all(tm <= m_l + 8.0f)) {     // defer-max (T13)
            const float mn    = fmaxf(m_l, tm);
            const float alpha = __builtin_amdgcn_exp2f(m_l - mn);
            m_l = mn;
            l_l *= alpha;
            #pragma unroll
            for (int p = 0; p < 2; ++p)
                #pragma unroll
                for (int r = 0; r < 16; ++r) oacc[p][r] *= alpha;
        }
        float rs = 0.f;
        #pragma unroll
        for (int p = 0; p < 2; ++p)
            #pragma unroll
            for (int r = 0; r < 16; ++r) {
                const float e = __builtin_amdgcn_exp2f(sacc[p][r] - m_l);
                sacc[p][r] = e;
                rs += e;
            }
        rs += __shfl_xor(rs, 32);
        l_l += rs;

        // ---- pack P to bf16 words: W[pos][i] covers rows {2i,2i+1} of D-layout
        unsigned W[2][8];
        #pragma unroll
        for (int p = 0; p < 2; ++p)
            #pragma unroll
            for (int i = 0; i < 8; ++i)
                W[p][i] = cvt_pk_bf16(sacc[p][2*i], sacc[p][2*i + 1]);

        // ---- PV: O(c,t) += V(c,s)·P(s,t); B=P via permlane32_swap exchange
        #pragma unroll
        for (int ks = 0; ks < 4; ++ks) {
            const int pos = ks >> 1, mp = ks & 1;
            uint2v e0 = __builtin_amdgcn_permlane32_swap(W[pos][4*mp + 0], W[pos][4*mp + 2], false, false);
            uint2v e1 = __builtin_amdgcn_permlane32_swap(W[pos][4*mp + 1], W[pos][4*mp + 3], false, false);
            union { unsigned u[4]; bf16x8 v; } bu;
            bu.u[0] = e0.x; bu.u[1] = e1.x; bu.u[2] = e0.y; bu.u[3] = e1.y;
            const bf16x8 bp = bu.v;
            #pragma unroll
            for (int cpos = 0; cpos < 2; ++cpos) {
                const bf16x8 av = *(const bf16x8*)(Vb + (32*cpos + lam)*ROWB +
                                                   (((2*ks + h) ^ swv) << 4));
                oacc[cpos] = __builtin_amdgcn_mfma_f32_32x32x16_bf16(av, bp, oacc[cpos], 0, 0, 0);
            }
        }
        __syncthreads();   // all waves done reading Kb/Vb before next overwrite
    }

    // ---- epilogue: lane-local normalize; stores are 128B-contiguous in t per row
    {
        const float inv = 1.0f / l_l;
        const int tg = t0 + 32*w + lam;
        #pragma unroll
        for (int cpos = 0; cpos < 2; ++cpos) {
            #pragma unroll
            for (int r = 0; r < 16; ++r) {
                const int c = 32*cpos + (r & 3) + 8*(r >> 2) + 4*h;
                out[(size_t)(head*64 + c) * SEQ + tg] = oacc[cpos][r] * inv;
            }
        }
    }
}

extern "C" void kernel_launch(void* const* d_in, const int* in_sizes, int n_in,
                              void* d_out, int out_size, void* d_ws, size_t ws_size,
                              hipStream_t stream) {
    const float* qkv = (const float*)d_in[0];
    float* out = (float*)d_out;
    qkv_attn_kernel<<<dim3(1024), dim3(256), 0, stream>>>(qkv, out);
}